// Round 19
// baseline (45.745 us; speedup 1.0000x reference)
//
#include <hip/hip_runtime.h>
#include <hip/hip_bf16.h>
#include <math.h>
#include <stdint.h>

#define N_RAYS    32768
#define N_SAMPLES (N_RAYS * 32)
#define THRESH 0.0001f
#define TBL_OFF  (16u * 1024u * 1024u)   // frag table after smp[] in d_ws

// record ids in frag table (one uint4 per lane per record)
#define R_A1   0   // +t (2)
#define R_A2   2   // +c (4)
#define R_R1A  6   // +2t+c (4)
#define R_R1B  10  // +t (2)
#define R_AR2  12  // +c (4)
#define R_AR2F 16  // +c (2)
#define R_B2I  18  // +i (4)
#define R_ARI  22  // +i (4)   -> 26 records total

typedef __attribute__((ext_vector_type(8)))  __bf16 bf16x8;
typedef __attribute__((ext_vector_type(16))) float  f32x16;
typedef float f4a __attribute__((ext_vector_type(4), aligned(4)));

union FragU  { __hip_bfloat162 h2[4]; uint32_t w[4]; bf16x8 v; };
union RecU   { bf16x8 v; uint4 u; };
union Rec16U { f32x16 v; uint4 u[4]; float f[16]; };
union H2U    { __hip_bfloat162 h; uint32_t u; };

__device__ inline __hip_bfloat162 pk2(float lo, float hi) {
    float2 t; t.x = lo; t.y = hi;
    return __float22bfloat162_rn(t);
}

__device__ inline bf16x8 pack8(const float* vals) {
    FragU u;
    u.h2[0] = pk2(vals[0], vals[1]);
    u.h2[1] = pk2(vals[2], vals[3]);
    u.h2[2] = pk2(vals[4], vals[5]);
    u.h2[3] = pk2(vals[6], vals[7]);
    return u.v;
}

__device__ inline float rcp_fast(float x) {
    float r;
    asm("v_rcp_f32 %0, %1" : "=v"(r) : "v"(x));
    return r;
}
__device__ inline float sigmoid_fast(float x) { return rcp_fast(1.0f + __expf(-x)); }
__device__ inline float softplus_fast(float x) {
    const float e = __expf(-fabsf(x));
    return fmaxf(x, 0.0f) + __logf(1.0f + e);
}

template <int P>
__device__ inline bf16x8 packB_relu(f32x16 a) {
    FragU u;
    u.h2[0] = pk2(fmaxf(a[P+0],0.f), fmaxf(a[P+1],0.f));
    u.h2[1] = pk2(fmaxf(a[P+2],0.f), fmaxf(a[P+3],0.f));
    u.h2[2] = pk2(fmaxf(a[P+4],0.f), fmaxf(a[P+5],0.f));
    u.h2[3] = pk2(fmaxf(a[P+6],0.f), fmaxf(a[P+7],0.f));
    return u.v;
}
template <int P>
__device__ inline bf16x8 packB_plain(f32x16 a) {
    FragU u;
    u.h2[0] = pk2(a[P+0], a[P+1]);
    u.h2[1] = pk2(a[P+2], a[P+3]);
    u.h2[2] = pk2(a[P+4], a[P+5]);
    u.h2[3] = pk2(a[P+6], a[P+7]);
    return u.v;
}

// ---------------------------------------------------------------------------
// Setup kernel: per-lane weight fragments for the 32x32x16 path (verified
// rounds 12-18). D layout: col=lane&31, row=(reg&3)+8*(reg>>2)+4*(lane>>5);
// rr(q,h) = (q&3)+8*(q>>2)+4*h.
// ---------------------------------------------------------------------------
__global__ __launch_bounds__(256) void nerf_build_frags(
    const float* __restrict__ w1,  const float* __restrict__ b1,
    const float* __restrict__ w2,  const float* __restrict__ b2,
    const float* __restrict__ w_sigma, const float* __restrict__ b_sigma,
    const float* __restrict__ w_rgb1,  const float* __restrict__ b_rgb1,
    const float* __restrict__ w_rgb2,  const float* __restrict__ b_rgb2,
    uint4* __restrict__ tbl)
{
    const int wid  = threadIdx.x >> 6;
    const int lane = threadIdx.x & 63;
    const int m    = lane & 31;
    const int h    = lane >> 5;
    RecU rec;

    if (wid == 0) {
        #pragma unroll
        for (int t = 0; t < 2; ++t) {        // A1: rows j=32t+m; k slots h=0,q0..3
            float v[8] = {0,0,0,0,0,0,0,0};
            if (h == 0) {
                const int j = 32*t + m;
                v[0] = w1[j]; v[1] = w1[64+j]; v[2] = w1[128+j]; v[3] = b1[j];
            }
            rec.v = pack8(v); tbl[(R_A1+t)*64 + lane] = rec.u;
        }
        #pragma unroll
        for (int c = 0; c < 4; ++c) {        // A2: A[f=m][j=16c+rr(q,h)] = w2[j*32+f]
            float v[8];
            #pragma unroll
            for (int q = 0; q < 8; ++q) {
                const int j = 16*c + (q&3) + 8*(q>>2) + 4*h;
                v[q] = w2[j*32 + m];
            }
            rec.v = pack8(v); tbl[(R_A2+c)*64 + lane] = rec.u;
        }
    } else if (wid == 1) {
        #pragma unroll
        for (int t = 0; t < 2; ++t)          // Ar1a: rows j=32t+m; k=f=16c+rr
            #pragma unroll
            for (int c = 0; c < 2; ++c) {
                float v[8];
                #pragma unroll
                for (int q = 0; q < 8; ++q) {
                    const int f = 16*c + (q&3) + 8*(q>>2) + 4*h;
                    v[q] = w_rgb1[f*64 + 32*t + m];
                }
                rec.v = pack8(v); tbl[(R_R1A+2*t+c)*64 + lane] = rec.u;
            }
        #pragma unroll
        for (int t = 0; t < 2; ++t) {        // Ar1b: dirs+bias on h=1 slots q0..3
            float v[8] = {0,0,0,0,0,0,0,0};
            if (h == 1) {
                const int j = 32*t + m;
                v[0] = w_rgb1[32*64 + j]; v[1] = w_rgb1[33*64 + j];
                v[2] = w_rgb1[34*64 + j]; v[3] = b_rgb1[j];
            }
            rec.v = pack8(v); tbl[(R_R1B+t)*64 + lane] = rec.u;
        }
    } else if (wid == 2) {
        #pragma unroll
        for (int c = 0; c < 4; ++c) {        // Ar2: rows m=0..2 rgb; k=hh=16c+rr
            float v[8];
            #pragma unroll
            for (int q = 0; q < 8; ++q) {
                const int hh = 16*c + (q&3) + 8*(q>>2) + 4*h;
                v[q] = (m < 3) ? w_rgb2[hh*3 + m] : 0.0f;
            }
            rec.v = pack8(v); tbl[(R_AR2+c)*64 + lane] = rec.u;
        }
        #pragma unroll
        for (int c = 0; c < 2; ++c) {        // Ar2f: w_sigma on row m=3; k=f=16c+rr
            float v[8];
            #pragma unroll
            for (int q = 0; q < 8; ++q) {
                const int f = 16*c + (q&3) + 8*(q>>2) + 4*h;
                v[q] = (m == 3) ? w_sigma[f] : 0.0f;
            }
            rec.v = pack8(v); tbl[(R_AR2F+c)*64 + lane] = rec.u;
        }
        Rec16U r16;
        #pragma unroll
        for (int i = 0; i < 4; ++i) {        // b2i: C-init, reg=4i+e -> b2[e+8i+4h]
            #pragma unroll
            for (int e = 0; e < 4; ++e) r16.f[4*i+e] = b2[e + 8*i + 4*h];
        }
        #pragma unroll
        for (int i = 0; i < 4; ++i) tbl[(R_B2I+i)*64 + lane] = r16.u[i];
        #pragma unroll
        for (int i = 0; i < 4; ++i) {        // arinit: row r=e+8i+4h
            #pragma unroll
            for (int e = 0; e < 4; ++e) {
                const int r = e + 8*i + 4*h;
                r16.f[4*i+e] = (r < 3) ? b_rgb2[r] : ((r == 3) ? b_sigma[0] : 0.0f);
            }
        }
        #pragma unroll
        for (int i = 0; i < 4; ++i) tbl[(R_ARI+i)*64 + lane] = r16.u[i];
    }
}

// ---------------------------------------------------------------------------
// Main MFMA MLP, 32x32x16, dual-stream, bf16x4 output (round-18 math) with
// ONE change: the pair loop is NOT unrolled (#pragma unroll 1) and uses
// explicit named double-buffer rotation. Loop body ~2.5 KB of code -> fits
// I-cache. Hypothesis: all prior fully-unrolled bodies (~10 KB) thrashed the
// I-cache, explaining ~85% per-SIMD issue-idle that was invariant to
// occupancy/ILP/structure.
// ---------------------------------------------------------------------------
__global__ __launch_bounds__(256, 2) void nerf_mlp_mfma(
    const float* __restrict__ samples,   // (N_SAMPLES, 7)
    const uint4* __restrict__ tbl,       // [26][64] frag table
    uint2* __restrict__ out)             // (N_SAMPLES): bf16x4 {tau, r, g, b}
{
    const int lane = threadIdx.x & 63;
    const int m32  = lane & 31;
    const int h    = lane >> 5;
    const int wgid = (blockIdx.x * blockDim.x + threadIdx.x) >> 6;  // 0..4095
    const int base0 = wgid * 256;        // 4 pairs x 64 samples

    // ---- pair-0 sample loads (named double-buffer, no arrays)
    f4a sa0, sb0, sa1, sb1;
    {
        const float* sp0 = samples + (size_t)(base0 + m32) * 7;
        const float* sp1 = samples + (size_t)(base0 + 32 + m32) * 7;
        sa0 = *(const f4a*)sp0;  sb0 = *(const f4a*)(sp0 + 3);
        sa1 = *(const f4a*)sp1;  sb1 = *(const f4a*)(sp1 + 3);
    }

    // ---- coalesced fragment loads
    bf16x8 A1[2], A2[4], R1a[4], R1b[2], Ar2[4], Ar2f[2];
    f32x16 b2i, arinit;
    {
        RecU r_;
        #pragma unroll
        for (int t = 0; t < 2; ++t) { r_.u = tbl[(R_A1+t)*64 + lane];  A1[t]  = r_.v; }
        #pragma unroll
        for (int c = 0; c < 4; ++c) { r_.u = tbl[(R_A2+c)*64 + lane];  A2[c]  = r_.v; }
        #pragma unroll
        for (int i = 0; i < 4; ++i) { r_.u = tbl[(R_R1A+i)*64 + lane]; R1a[i] = r_.v; }
        #pragma unroll
        for (int t = 0; t < 2; ++t) { r_.u = tbl[(R_R1B+t)*64 + lane]; R1b[t] = r_.v; }
        #pragma unroll
        for (int c = 0; c < 4; ++c) { r_.u = tbl[(R_AR2+c)*64 + lane]; Ar2[c] = r_.v; }
        #pragma unroll
        for (int c = 0; c < 2; ++c) { r_.u = tbl[(R_AR2F+c)*64 + lane]; Ar2f[c] = r_.v; }
        Rec16U r16;
        #pragma unroll
        for (int i = 0; i < 4; ++i) r16.u[i] = tbl[(R_B2I+i)*64 + lane];
        b2i = r16.v;
        #pragma unroll
        for (int i = 0; i < 4; ++i) r16.u[i] = tbl[(R_ARI+i)*64 + lane];
        arinit = r16.v;
    }

    const f32x16 zero16 = {0,0,0,0,0,0,0,0,0,0,0,0,0,0,0,0};

    #pragma unroll 1
    for (int it = 0; it < 4; ++it) {
        // ---- prefetch next pair (clamped on last iter; overwritten unused)
        f4a na0, nb0, na1, nb1;
        {
            const int nit = (it < 3) ? (it + 1) : 3;
            const int nbase = base0 + nit * 64;
            const float* sp0 = samples + (size_t)(nbase + m32) * 7;
            const float* sp1 = samples + (size_t)(nbase + 32 + m32) * 7;
            na0 = *(const f4a*)sp0;  nb0 = *(const f4a*)(sp0 + 3);
            na1 = *(const f4a*)sp1;  nb1 = *(const f4a*)(sp1 + 3);
        }

        // merged input kstep per stream: h=0 lanes pos+1, h=1 lanes dirs+1
        FragU bin[2];
        bin[0].h2[0] = pk2(h ? sb0.x : sa0.x, h ? sb0.y : sa0.y);
        bin[0].h2[1] = pk2(h ? sb0.z : sa0.z, 1.0f);
        bin[0].w[2] = 0; bin[0].w[3] = 0;
        bin[1].h2[0] = pk2(h ? sb1.x : sa1.x, h ? sb1.y : sa1.y);
        bin[1].h2[1] = pk2(h ? sb1.z : sa1.z, 1.0f);
        bin[1].w[2] = 0; bin[1].w[3] = 0;

        // layer1: 2 tiles x 2 streams (4 independent MFMAs)
        f32x16 accL1[2][2];
        #pragma unroll
        for (int t = 0; t < 2; ++t)
            #pragma unroll
            for (int s = 0; s < 2; ++s)
                accL1[s][t] = __builtin_amdgcn_mfma_f32_32x32x16_bf16(A1[t], bin[s].v, zero16, 0,0,0);

        bf16x8 B2c[2][4];
        #pragma unroll
        for (int s = 0; s < 2; ++s) {
            B2c[s][0] = packB_relu<0>(accL1[s][0]);
            B2c[s][1] = packB_relu<8>(accL1[s][0]);
            B2c[s][2] = packB_relu<0>(accL1[s][1]);
            B2c[s][3] = packB_relu<8>(accL1[s][1]);
        }

        // layer2: 4-kstep chain per stream, streams interleaved
        f32x16 accL2[2];
        #pragma unroll
        for (int s = 0; s < 2; ++s)
            accL2[s] = __builtin_amdgcn_mfma_f32_32x32x16_bf16(A2[0], B2c[s][0], b2i, 0,0,0);
        #pragma unroll
        for (int c = 1; c < 4; ++c)
            #pragma unroll
            for (int s = 0; s < 2; ++s)
                accL2[s] = __builtin_amdgcn_mfma_f32_32x32x16_bf16(A2[c], B2c[s][c], accL2[s], 0,0,0);

        bf16x8 Bf[2][2];
        #pragma unroll
        for (int s = 0; s < 2; ++s) {
            Bf[s][0] = packB_plain<0>(accL2[s]);
            Bf[s][1] = packB_plain<8>(accL2[s]);
        }

        // rgb1: 2 tiles x 2 streams, 3-deep chains interleaved
        f32x16 ah[2][2];
        #pragma unroll
        for (int t = 0; t < 2; ++t)
            #pragma unroll
            for (int s = 0; s < 2; ++s) {
                ah[s][t] = __builtin_amdgcn_mfma_f32_32x32x16_bf16(R1a[2*t+0], Bf[s][0], zero16, 0,0,0);
                ah[s][t] = __builtin_amdgcn_mfma_f32_32x32x16_bf16(R1a[2*t+1], Bf[s][1], ah[s][t], 0,0,0);
                ah[s][t] = __builtin_amdgcn_mfma_f32_32x32x16_bf16(R1b[t],     bin[s].v, ah[s][t], 0,0,0);
            }

        bf16x8 Bh[2][4];
        #pragma unroll
        for (int s = 0; s < 2; ++s) {
            Bh[s][0] = packB_relu<0>(ah[s][0]);
            Bh[s][1] = packB_relu<8>(ah[s][0]);
            Bh[s][2] = packB_relu<0>(ah[s][1]);
            Bh[s][3] = packB_relu<8>(ah[s][1]);
        }

        // rgb2 (+sigma row 3): 6-kstep chain per stream, interleaved
        f32x16 ar[2];
        #pragma unroll
        for (int s = 0; s < 2; ++s)
            ar[s] = __builtin_amdgcn_mfma_f32_32x32x16_bf16(Ar2[0], Bh[s][0], arinit, 0,0,0);
        #pragma unroll
        for (int c = 1; c < 4; ++c)
            #pragma unroll
            for (int s = 0; s < 2; ++s)
                ar[s] = __builtin_amdgcn_mfma_f32_32x32x16_bf16(Ar2[c], Bh[s][c], ar[s], 0,0,0);
        #pragma unroll
        for (int c = 0; c < 2; ++c)
            #pragma unroll
            for (int s = 0; s < 2; ++s)
                ar[s] = __builtin_amdgcn_mfma_f32_32x32x16_bf16(Ar2f[c], Bf[s][c], ar[s], 0,0,0);

        // epilogue per stream
        {
            const float rr    = sigmoid_fast(ar[0][0]);
            const float gg    = sigmoid_fast(ar[0][1]);
            const float bb    = sigmoid_fast(ar[0][2]);
            const float sigma = softplus_fast(ar[0][3]);
            const float tau   = sigma * sb0.w;
            if (lane < 32) {
                H2U lo, hi;
                lo.h = pk2(tau, rr);
                hi.h = pk2(gg, bb);
                out[base0 + it * 64 + m32] = make_uint2(lo.u, hi.u);
            }
        }
        {
            const float rr    = sigmoid_fast(ar[1][0]);
            const float gg    = sigmoid_fast(ar[1][1]);
            const float bb    = sigmoid_fast(ar[1][2]);
            const float sigma = softplus_fast(ar[1][3]);
            const float tau   = sigma * sb1.w;
            if (lane < 32) {
                H2U lo, hi;
                lo.h = pk2(tau, rr);
                hi.h = pk2(gg, bb);
                out[base0 + it * 64 + 32 + m32] = make_uint2(lo.u, hi.u);
            }
        }

        // rotate double buffers (register movs)
        sa0 = na0; sb0 = nb0; sa1 = na1; sb1 = nb1;
    }
}

// ---------------------------------------------------------------------------
// Kernel 2: one wave per ray — scan tau, gate, reduce (bf16x4 input records).
// ---------------------------------------------------------------------------
__global__ __launch_bounds__(256) void nerf_render_kernel(
    const uint2* __restrict__ smp,       // (N_SAMPLES): bf16x4 {tau, r, g, b}
    const int*   __restrict__ packing,
    const float* __restrict__ bg,
    float*       __restrict__ out)
{
    const int gtid = blockIdx.x * blockDim.x + threadIdx.x;
    const int ray  = gtid >> 6;
    const int lane = threadIdx.x & 63;
    if (ray >= N_RAYS) return;

    const int start = packing[2 * ray];
    const int count = packing[2 * ray + 1];

    float tau = 0.0f, r = 0.0f, g = 0.0f, b = 0.0f;
    if (lane < count) {
        const uint2 v = smp[start + lane];
        H2U lo, hi;
        lo.u = v.x; hi.u = v.y;
        tau = __bfloat162float(lo.h.x); r = __bfloat162float(lo.h.y);
        g   = __bfloat162float(hi.h.x); b = __bfloat162float(hi.h.y);
    }

    float incl = tau;
    #pragma unroll
    for (int off = 1; off < 64; off <<= 1) {
        const float v = __shfl_up(incl, off, 64);
        if (lane >= off) incl += v;
    }
    const float c_excl = incl - tau;

    const float T     = __expf(-c_excl);
    const float alpha = 1.0f - __expf(-tau);
    float w = (lane < count && T > THRESH) ? T * alpha : 0.0f;

    float cr = r * w, cg = g * w, cb = b * w;

    #pragma unroll
    for (int off = 32; off > 0; off >>= 1) {
        cr += __shfl_down(cr, off, 64);
        cg += __shfl_down(cg, off, 64);
        cb += __shfl_down(cb, off, 64);
        w  += __shfl_down(w,  off, 64);
    }

    if (lane == 0) {
        out[ray * 3 + 0] = cr + bg[0] * (1.0f - w);
        out[ray * 3 + 1] = cg + bg[1] * (1.0f - w);
        out[ray * 3 + 2] = cb + bg[2] * (1.0f - w);
    }
}

extern "C" void kernel_launch(void* const* d_in, const int* in_sizes, int n_in,
                              void* d_out, int out_size, void* d_ws, size_t ws_size,
                              hipStream_t stream) {
    const float* samples  = (const float*)d_in[0];
    const int*   packing  = (const int*)  d_in[1];
    const float* w1       = (const float*)d_in[3];
    const float* b1       = (const float*)d_in[4];
    const float* w2       = (const float*)d_in[5];
    const float* b2       = (const float*)d_in[6];
    const float* w_sigma  = (const float*)d_in[7];
    const float* b_sigma  = (const float*)d_in[8];
    const float* w_rgb1   = (const float*)d_in[9];
    const float* b_rgb1   = (const float*)d_in[10];
    const float* w_rgb2   = (const float*)d_in[11];
    const float* b_rgb2   = (const float*)d_in[12];
    const float* bg       = (const float*)d_in[13];

    uint2* smp = (uint2*)d_ws;                           // 8 MiB (bf16x4/sample)
    uint4* tbl = (uint4*)((char*)d_ws + TBL_OFF);        // 26x64x16B frag table
    float* out = (float*)d_out;

    nerf_build_frags<<<1, 256, 0, stream>>>(
        w1, b1, w2, b2, w_sigma, b_sigma,
        w_rgb1, b_rgb1, w_rgb2, b_rgb2, tbl);

    // 1024 blocks x 4 waves = 4096 waves x 4 pairs x 64 samples = N_SAMPLES
    nerf_mlp_mfma<<<1024, 256, 0, stream>>>(samples, tbl, smp);

    nerf_render_kernel<<<(N_RAYS * 64) / 256, 256, 0, stream>>>(smp, packing, bg, out);
}